// Round 3
// baseline (232.300 us; speedup 1.0000x reference)
//
#include <hip/hip_runtime.h>

// ---------------------------------------------------------------------------
// GMMConv forward, three kernels (all barrier-free):
//  0) convert_W: Wp[j'][k] = bf16(W_fc[((j'&3)<<6)|(j'>>2)][k]).  Wp lives in
//     a 128 KB corner of d_out (edge_aggregate rewrites all of d_out later,
//     strictly after gemm finishes -> safe overlay, no extra ws needed).
//  1) gemm_direct: node_feat = feat @ Wp.T via MFMA 16x16x32 bf16 with NO
//     LDS and NO barriers: K=256 is tiny, W is L2-resident, A-frags are read
//     straight from fp32 global and converted in-reg (0.65 us chip-wide).
//     Output nf bf16 permuted [m][f*4+k] so the edge gather is one ushort4.
//  2) edge_aggregate: one wave per destination node (CSR rowptr sorts edges
//     by dst -> no atomics). Chunked cooperative gaussians in LDS; gather
//     loop has a fixed-16 fully-unrolled fast path for 16 loads in flight.
// ---------------------------------------------------------------------------

typedef __attribute__((ext_vector_type(8))) short bf16x8;
typedef __attribute__((ext_vector_type(4))) float f32x4;

__device__ inline unsigned short f32_to_bf16(float f) {
    union { float f; unsigned int u; } c; c.f = f;
    unsigned int u = c.u;
    u += 0x7fffu + ((u >> 16) & 1u);   // round-to-nearest-even
    return (unsigned short)(u >> 16);
}
__device__ inline float bf16_to_f32(unsigned short h) {
    union { unsigned int u; float f; } c; c.u = ((unsigned int)h) << 16;
    return c.f;
}

// W_fc fp32 [256][256] -> Wp bf16 [256][256], rows permuted: Wp[j'] = W[(j'&3)*64 + (j'>>2)]
__global__ __launch_bounds__(256) void convert_W(
    const float* __restrict__ W, unsigned short* __restrict__ Wp)
{
    const int t = blockIdx.x * 256 + threadIdx.x;   // grid 32 -> 8192 threads
#pragma unroll
    for (int r = 0; r < 2; ++r) {
        const int fi = t + r * 8192;                // float4 index, 16384 total
        const int jp = fi >> 6;                     // 0..255
        const int k4 = fi & 63;
        const int wrow = ((jp & 3) << 6) | (jp >> 2);
        const float4 v = reinterpret_cast<const float4*>(W)[wrow * 64 + k4];
        ushort4 h;
        h.x = f32_to_bf16(v.x); h.y = f32_to_bf16(v.y);
        h.z = f32_to_bf16(v.z); h.w = f32_to_bf16(v.w);
        reinterpret_cast<ushort4*>(Wp)[jp * 64 + k4] = h;
    }
}

// C[m][j'] = sum_k A[m][k] * Wp[j'][k].  Block = 256 thr = 4 waves; block
// tile 64 rows x 256 cols (wave w -> cols w*64..w*64+63). No LDS/barriers.
__global__ __launch_bounds__(256) void gemm_direct(
    const float* __restrict__ A,            // feat [M][256] fp32
    const unsigned short* __restrict__ Wp,  // bf16 [256][256] permuted rows
    unsigned short* __restrict__ C,         // nf bf16 [M][256]
    int M)
{
    const int t    = threadIdx.x;
    const int lane = t & 63;
    const int wave = t >> 6;
    const int wn   = wave * 64;
    const int bm   = blockIdx.x * 64;
    const int l16  = lane & 15;
    const int quad = lane >> 4;

    f32x4 acc[4][4];
#pragma unroll
    for (int mi = 0; mi < 4; ++mi)
#pragma unroll
        for (int ni = 0; ni < 4; ++ni)
            acc[mi][ni] = (f32x4){0.f, 0.f, 0.f, 0.f};

    // clamped A rows (reads stay in-bounds; OOB rows masked at store)
    int arow[4];
#pragma unroll
    for (int mi = 0; mi < 4; ++mi) {
        int r = bm + mi * 16 + l16;
        arow[mi] = r < M ? r : (M - 1);
    }

#pragma unroll 2
    for (int k0 = 0; k0 < 256; k0 += 32) {
        bf16x8 af[4], bfr[4];
#pragma unroll
        for (int ni = 0; ni < 4; ++ni)
            bfr[ni] = *reinterpret_cast<const bf16x8*>(
                Wp + (size_t)(wn + ni * 16 + l16) * 256 + k0 + quad * 8);
#pragma unroll
        for (int mi = 0; mi < 4; ++mi) {
            const float* p = A + (size_t)arow[mi] * 256 + k0 + quad * 8;
            const float4 a0 = *reinterpret_cast<const float4*>(p);
            const float4 a1 = *reinterpret_cast<const float4*>(p + 4);
            union { bf16x8 v; unsigned short s[8]; } pk;
            pk.s[0] = f32_to_bf16(a0.x); pk.s[1] = f32_to_bf16(a0.y);
            pk.s[2] = f32_to_bf16(a0.z); pk.s[3] = f32_to_bf16(a0.w);
            pk.s[4] = f32_to_bf16(a1.x); pk.s[5] = f32_to_bf16(a1.y);
            pk.s[6] = f32_to_bf16(a1.z); pk.s[7] = f32_to_bf16(a1.w);
            af[mi] = pk.v;
        }
#pragma unroll
        for (int mi = 0; mi < 4; ++mi)
#pragma unroll
            for (int ni = 0; ni < 4; ++ni)
                acc[mi][ni] = __builtin_amdgcn_mfma_f32_16x16x32_bf16(
                    af[mi], bfr[ni], acc[mi][ni], 0, 0, 0);
    }

    // C/D layout: col = lane&15, row = quad*4 + reg   [m89-verified]
#pragma unroll
    for (int mi = 0; mi < 4; ++mi) {
#pragma unroll
        for (int r = 0; r < 4; ++r) {
            const int row = bm + mi * 16 + quad * 4 + r;
            if (row < M) {
#pragma unroll
                for (int ni = 0; ni < 4; ++ni) {
                    const int col = wn + ni * 16 + l16;
                    C[(size_t)row * 256 + col] = f32_to_bf16(acc[mi][ni][r]);
                }
            }
        }
    }
}

// One wave per destination node; lane = feature f (F=64).
__global__ __launch_bounds__(256) void edge_aggregate(
    const int* __restrict__ rowptr,
    const int* __restrict__ colind,
    const float* __restrict__ pseudo,       // [E][2]
    const unsigned short* __restrict__ nf,  // bf16 [N][256] permuted [f*4+k]
    const float* __restrict__ mu,           // [4][2]
    const float* __restrict__ inv_sigma,    // [4][2]
    const float* __restrict__ bias,         // [64]
    float* __restrict__ out,                // [N][64]
    int N)
{
    __shared__ float gbuf[4][64];   // per-wave: 16 edges x 4 kernels
    __shared__ int   cbuf[4][16];   // per-wave: 16 colinds
    const int wave = threadIdx.x >> 6;
    const int lane = threadIdx.x & 63;
    const int node = blockIdx.x * 4 + wave;
    if (node >= N) return;          // wave-uniform exit; no block barriers below

    const int kk = lane >> 4;       // gaussian kernel this lane computes
    const int ii = lane & 15;       // edge slot this lane computes
    const float mx = mu[2 * kk], my = mu[2 * kk + 1];
    const float sa = inv_sigma[2 * kk], sb = inv_sigma[2 * kk + 1];
    const float sx = sa * sa, sy = sb * sb;

    const int e0 = rowptr[node];
    const int e1 = rowptr[node + 1];

    float* gw = gbuf[wave];
    int*   cw = cbuf[wave];

    float acc = 0.f;
    for (int ec = e0; ec < e1; ec += 16) {
        const int cnt = min(16, e1 - ec);
        if (ii < cnt) {
            const int e = ec + ii;
            const float2 p = *reinterpret_cast<const float2*>(pseudo + 2 * (size_t)e);
            const float dx = p.x - mx, dy = p.y - my;
            gw[ii * 4 + kk] = __expf(-0.5f * (dx * dx * sx + dy * dy * sy));
            if (kk == 0) cw[ii] = colind[e];
        }
        __builtin_amdgcn_wave_barrier();
        __threadfence_block();      // drain LDS writes before broadcast reads
        if (cnt == 16) {            // fixed trip count -> full unroll -> 16 gathers in flight
#pragma unroll
            for (int i2 = 0; i2 < 16; ++i2) {
                const int col = cw[i2];
                const float4 g = *reinterpret_cast<const float4*>(&gw[i2 * 4]);
                const ushort4 h = *reinterpret_cast<const ushort4*>(
                    nf + ((size_t)col << 8) + (lane << 2));
                acc += g.x * bf16_to_f32(h.x) + g.y * bf16_to_f32(h.y)
                     + g.z * bf16_to_f32(h.z) + g.w * bf16_to_f32(h.w);
            }
        } else {
            for (int i2 = 0; i2 < cnt; ++i2) {
                const int col = cw[i2];
                const float4 g = *reinterpret_cast<const float4*>(&gw[i2 * 4]);
                const ushort4 h = *reinterpret_cast<const ushort4*>(
                    nf + ((size_t)col << 8) + (lane << 2));
                acc += g.x * bf16_to_f32(h.x) + g.y * bf16_to_f32(h.y)
                     + g.z * bf16_to_f32(h.z) + g.w * bf16_to_f32(h.w);
            }
        }
        __builtin_amdgcn_wave_barrier();
        __threadfence_block();      // reads done before next chunk's writes
    }
    out[((size_t)node << 6) + lane] = acc + bias[lane];
}

extern "C" void kernel_launch(void* const* d_in, const int* in_sizes, int n_in,
                              void* d_out, int out_size, void* d_ws, size_t ws_size,
                              hipStream_t stream)
{
    const int*   rowptr    = (const int*)d_in[0];
    const int*   colind    = (const int*)d_in[1];
    // d_in[2] colptr, d_in[3] rowind, d_in[4] permute: inert in forward math
    const float* feat      = (const float*)d_in[5];
    const float* pseudo    = (const float*)d_in[6];
    const float* W_fc      = (const float*)d_in[7];
    const float* mu        = (const float*)d_in[8];
    const float* inv_sigma = (const float*)d_in[9];
    const float* bias      = (const float*)d_in[10];
    float* out = (float*)d_out;
    unsigned short* nf = (unsigned short*)d_ws;     // 50000*256*2 = 25.6 MB
    unsigned short* Wp = (unsigned short*)d_out;    // 128 KB overlay; edge_aggregate
                                                    // rewrites d_out after gemm is done

    const int N = in_sizes[0] - 1;   // 50000

    hipLaunchKernelGGL(convert_W, dim3(32), dim3(256), 0, stream, W_fc, Wp);

    const int gBlocks = (N + 63) / 64;   // 782
    hipLaunchKernelGGL(gemm_direct, dim3(gBlocks), dim3(256), 0, stream, feat, Wp, nf, N);

    const int blocks = (N + 3) / 4;      // 4 waves (nodes) per 256-thread block
    hipLaunchKernelGGL(edge_aggregate, dim3(blocks), dim3(256), 0, stream,
                       rowptr, colind, pseudo, nf, mu, inv_sigma, bias, out, N);
}

// Round 4
// 198.624 us; speedup vs baseline: 1.1695x; 1.1695x over previous
//
#include <hip/hip_runtime.h>

// ---------------------------------------------------------------------------
// GMMConv forward:
//  0) convert_inputs: Wp[j'][k]=bf16(W_fc[((j'&3)<<6)|(j'>>2)][k]) (permuted
//     so nf layout becomes [m][f*4+k]); Af = bf16(feat). One streaming pass.
//  1) gemm_lds: nf = Af @ Wp.T, m97-style: 128x128 tile, global_load_lds
//     width=16 into unpadded 64B-row LDS tiles, 16x16x32 bf16 MFMA.
//     Grid (2,391), bn fastest -> A tile reused across the 2 column blocks.
//  2) edge_aggregate: round-2 body verbatim (rolled gather loop measured
//     faster than unrolled-16). One wave per dst node, no atomics.
//  Fast path needs 51.2 MB ws (nf 25.6 + Af 25.6); else round-2 fallback GEMM.
// ---------------------------------------------------------------------------

typedef __attribute__((ext_vector_type(8))) short bf16x8;
typedef __attribute__((ext_vector_type(4))) float f32x4;

__device__ inline unsigned short f32_to_bf16(float f) {
    union { float f; unsigned int u; } c; c.f = f;
    unsigned int u = c.u;
    u += 0x7fffu + ((u >> 16) & 1u);   // round-to-nearest-even
    return (unsigned short)(u >> 16);
}
__device__ inline float bf16_to_f32(unsigned short h) {
    union { unsigned int u; float f; } c; c.u = ((unsigned int)h) << 16;
    return c.f;
}
__device__ inline ushort4 cvt4(float4 v) {
    ushort4 h;
    h.x = f32_to_bf16(v.x); h.y = f32_to_bf16(v.y);
    h.z = f32_to_bf16(v.z); h.w = f32_to_bf16(v.w);
    return h;
}

// W permute+convert (first 16384 float4) + feat convert (grid-stride).
__global__ __launch_bounds__(256) void convert_inputs(
    const float* __restrict__ W, const float* __restrict__ feat,
    unsigned short* __restrict__ Wp, unsigned short* __restrict__ Af,
    int nFeat4)
{
    const int gid = blockIdx.x * 256 + threadIdx.x;
    if (gid < 16384) {
        const int jp = gid >> 6, k4 = gid & 63;
        const int wrow = ((jp & 3) << 6) | (jp >> 2);
        reinterpret_cast<ushort4*>(Wp)[jp * 64 + k4] =
            cvt4(reinterpret_cast<const float4*>(W)[wrow * 64 + k4]);
    }
    for (int i = gid; i < nFeat4; i += gridDim.x * 256)
        reinterpret_cast<ushort4*>(Af)[i] =
            cvt4(reinterpret_cast<const float4*>(feat)[i]);
}

// C[m][j'] = sum_k Af[m][k] * Wp[j'][k].  m97 structure.
__global__ void gemm_lds(
    const unsigned short* __restrict__ Af,  // bf16 [M][256]
    const unsigned short* __restrict__ Wp,  // bf16 [256][256]
    unsigned short* __restrict__ C,         // nf bf16 [M][256]
    int M)
{
    __shared__ unsigned short As[128 * 32];  // 8 KB, row stride 64 B (NO pad:
    __shared__ unsigned short Bs[128 * 32];  // required by global_load_lds)
    const int t    = threadIdx.x;
    const int lane = t & 63;
    const int wave = t >> 6;
    const int bn   = blockIdx.x * 128;       // 0 or 128 (fastest -> A reuse)
    const int bm   = blockIdx.y * 128;
    const int l16  = lane & 15;
    const int quad = lane >> 4;
    const int wm   = (wave >> 1) * 64;
    const int wn   = (wave & 1) * 64;

    // staging: wave w loads 1 KB chunks {2w, 2w+1} of each tile.
    // chunk c, lane l -> LDS byte c*1024 + l*16 == tile row c*16+(l>>2),
    // k elem (l&3)*8.
    const int r0 = wave * 32 + (lane >> 2);  // chunk 2w row
    const int r1 = r0 + 16;                  // chunk 2w+1 row
    const int kc = (lane & 3) * 8;
    const size_t ar0 = (size_t)min(bm + r0, M - 1) * 256 + kc;
    const size_t ar1 = (size_t)min(bm + r1, M - 1) * 256 + kc;
    const size_t br0 = (size_t)(bn + r0) * 256 + kc;
    const size_t br1 = (size_t)(bn + r1) * 256 + kc;

    f32x4 acc[4][4];
#pragma unroll
    for (int mi = 0; mi < 4; ++mi)
#pragma unroll
        for (int ni = 0; ni < 4; ++ni)
            acc[mi][ni] = (f32x4){0.f, 0.f, 0.f, 0.f};

    typedef __attribute__((address_space(3))) void lds_t;
    typedef const __attribute__((address_space(1))) void gm_t;

    for (int k0 = 0; k0 < 256; k0 += 32) {
        __builtin_amdgcn_global_load_lds((gm_t*)(Af + ar0 + k0),
            (lds_t*)(As + wave * 1024), 16, 0, 0);
        __builtin_amdgcn_global_load_lds((gm_t*)(Af + ar1 + k0),
            (lds_t*)(As + wave * 1024 + 512), 16, 0, 0);
        __builtin_amdgcn_global_load_lds((gm_t*)(Wp + br0 + k0),
            (lds_t*)(Bs + wave * 1024), 16, 0, 0);
        __builtin_amdgcn_global_load_lds((gm_t*)(Wp + br1 + k0),
            (lds_t*)(Bs + wave * 1024 + 512), 16, 0, 0);
        __syncthreads();

        bf16x8 af[4], bfr[4];
#pragma unroll
        for (int mi = 0; mi < 4; ++mi)
            af[mi] = *reinterpret_cast<const bf16x8*>(
                &As[(wm + mi * 16 + l16) * 32 + quad * 8]);
#pragma unroll
        for (int ni = 0; ni < 4; ++ni)
            bfr[ni] = *reinterpret_cast<const bf16x8*>(
                &Bs[(wn + ni * 16 + l16) * 32 + quad * 8]);
#pragma unroll
        for (int mi = 0; mi < 4; ++mi)
#pragma unroll
            for (int ni = 0; ni < 4; ++ni)
                acc[mi][ni] = __builtin_amdgcn_mfma_f32_16x16x32_bf16(
                    af[mi], bfr[ni], acc[mi][ni], 0, 0, 0);
        __syncthreads();
    }

    // C/D layout: col = lane&15, row = quad*4 + reg   [m89-verified]
#pragma unroll
    for (int mi = 0; mi < 4; ++mi) {
#pragma unroll
        for (int r = 0; r < 4; ++r) {
            const int row = bm + wm + mi * 16 + quad * 4 + r;
            if (row < M) {
#pragma unroll
                for (int ni = 0; ni < 4; ++ni) {
                    const int col = bn + wn + ni * 16 + l16;
                    C[(size_t)row * 256 + col] = f32_to_bf16(acc[mi][ni][r]);
                }
            }
        }
    }
}

// Fallback GEMM (round-2): fp32 inputs staged+converted through LDS.
#define LDST 40
__global__ __launch_bounds__(256, 2) void gemm_fallback(
    const float* __restrict__ A, const float* __restrict__ W,
    unsigned short* __restrict__ C, int M)
{
    __shared__ unsigned short As[128 * LDST];
    __shared__ unsigned short Bs[128 * LDST];
    const int t    = threadIdx.x;
    const int lane = t & 63;
    const int wave = t >> 6;
    const int wm   = (wave >> 1) * 64;
    const int wn   = (wave & 1) * 64;
    const int bm   = blockIdx.x * 128;
    const int bn   = blockIdx.y * 128;
    const int l16  = lane & 15;
    const int quad = lane >> 4;

    f32x4 acc[4][4];
#pragma unroll
    for (int mi = 0; mi < 4; ++mi)
#pragma unroll
        for (int ni = 0; ni < 4; ++ni)
            acc[mi][ni] = (f32x4){0.f, 0.f, 0.f, 0.f};

    for (int k0 = 0; k0 < 256; k0 += 32) {
#pragma unroll
        for (int i = 0; i < 4; ++i) {
            const int flat = (i * 256 + t) * 4;
            const int row  = flat >> 5;
            const int off  = flat & 31;
            const int grow = bm + row;
            float4 av = make_float4(0.f, 0.f, 0.f, 0.f);
            if (grow < M)
                av = *reinterpret_cast<const float4*>(A + (size_t)grow * 256 + k0 + off);
            const int jp   = bn + row;
            const int wrow = ((jp & 3) << 6) | (jp >> 2);
            const float4 wv = *reinterpret_cast<const float4*>(W + (size_t)wrow * 256 + k0 + off);
            *reinterpret_cast<ushort4*>(&As[row * LDST + off]) = cvt4(av);
            *reinterpret_cast<ushort4*>(&Bs[row * LDST + off]) = cvt4(wv);
        }
        __syncthreads();
        bf16x8 af[4], bfr[4];
#pragma unroll
        for (int mi = 0; mi < 4; ++mi)
            af[mi] = *reinterpret_cast<const bf16x8*>(&As[(wm + mi * 16 + l16) * LDST + quad * 8]);
#pragma unroll
        for (int ni = 0; ni < 4; ++ni)
            bfr[ni] = *reinterpret_cast<const bf16x8*>(&Bs[(wn + ni * 16 + l16) * LDST + quad * 8]);
#pragma unroll
        for (int mi = 0; mi < 4; ++mi)
#pragma unroll
            for (int ni = 0; ni < 4; ++ni)
                acc[mi][ni] = __builtin_amdgcn_mfma_f32_16x16x32_bf16(
                    af[mi], bfr[ni], acc[mi][ni], 0, 0, 0);
        __syncthreads();
    }
#pragma unroll
    for (int mi = 0; mi < 4; ++mi) {
#pragma unroll
        for (int r = 0; r < 4; ++r) {
            const int row = bm + wm + mi * 16 + quad * 4 + r;
            if (row < M) {
#pragma unroll
                for (int ni = 0; ni < 4; ++ni) {
                    const int col = bn + wn + ni * 16 + l16;
                    C[(size_t)row * 256 + col] = f32_to_bf16(acc[mi][ni][r]);
                }
            }
        }
    }
}

// One wave per destination node; lane = feature f (F=64). Round-2 body.
__global__ __launch_bounds__(256) void edge_aggregate(
    const int* __restrict__ rowptr,
    const int* __restrict__ colind,
    const float* __restrict__ pseudo,       // [E][2]
    const unsigned short* __restrict__ nf,  // bf16 [N][256] permuted [f*4+k]
    const float* __restrict__ mu,
    const float* __restrict__ inv_sigma,
    const float* __restrict__ bias,
    float* __restrict__ out,                // [N][64]
    int N)
{
    __shared__ float gbuf[4][64];
    __shared__ int   cbuf[4][16];
    const int wave = threadIdx.x >> 6;
    const int lane = threadIdx.x & 63;
    const int node = blockIdx.x * 4 + wave;
    if (node >= N) return;          // wave-uniform exit; no block barriers below

    const int kk = lane >> 4;
    const int ii = lane & 15;
    const float mx = mu[2 * kk], my = mu[2 * kk + 1];
    const float sa = inv_sigma[2 * kk], sb = inv_sigma[2 * kk + 1];
    const float sx = sa * sa, sy = sb * sb;

    const int e0 = rowptr[node];
    const int e1 = rowptr[node + 1];
    float* gw = gbuf[wave];
    int*   cw = cbuf[wave];

    float acc = 0.f;
    for (int ec = e0; ec < e1; ec += 16) {
        const int cnt = min(16, e1 - ec);
        if (ii < cnt) {
            const int e = ec + ii;
            const float2 p = *reinterpret_cast<const float2*>(pseudo + 2 * (size_t)e);
            const float dx = p.x - mx, dy = p.y - my;
            gw[ii * 4 + kk] = __expf(-0.5f * (dx * dx * sx + dy * dy * sy));
            if (kk == 0) cw[ii] = colind[e];
        }
        __builtin_amdgcn_wave_barrier();
        __threadfence_block();
        for (int i2 = 0; i2 < cnt; ++i2) {
            const int col = cw[i2];
            const float4 g = *reinterpret_cast<const float4*>(&gw[i2 * 4]);
            const ushort4 h = *reinterpret_cast<const ushort4*>(
                nf + ((size_t)col << 8) + (lane << 2));
            acc += g.x * bf16_to_f32(h.x) + g.y * bf16_to_f32(h.y)
                 + g.z * bf16_to_f32(h.z) + g.w * bf16_to_f32(h.w);
        }
        __builtin_amdgcn_wave_barrier();
        __threadfence_block();
    }
    out[((size_t)node << 6) + lane] = acc + bias[lane];
}

extern "C" void kernel_launch(void* const* d_in, const int* in_sizes, int n_in,
                              void* d_out, int out_size, void* d_ws, size_t ws_size,
                              hipStream_t stream)
{
    const int*   rowptr    = (const int*)d_in[0];
    const int*   colind    = (const int*)d_in[1];
    const float* feat      = (const float*)d_in[5];
    const float* pseudo    = (const float*)d_in[6];
    const float* W_fc      = (const float*)d_in[7];
    const float* mu        = (const float*)d_in[8];
    const float* inv_sigma = (const float*)d_in[9];
    const float* bias      = (const float*)d_in[10];
    float* out = (float*)d_out;

    const int N = in_sizes[0] - 1;                 // 50000
    unsigned short* nf = (unsigned short*)d_ws;    // bf16 [N][256] = 25.6 MB
    const size_t nfElems = (size_t)N * 256;

    if (ws_size >= nfElems * 4) {
        // fast path: Af bf16 [N][256] right after nf in ws
        unsigned short* Af = nf + nfElems;
        unsigned short* Wp = (unsigned short*)d_out;   // 128 KB overlay;
                                                       // edge rewrites d_out later
        hipLaunchKernelGGL(convert_inputs, dim3(1024), dim3(256), 0, stream,
                           W_fc, feat, Wp, Af, N * 64);
        hipLaunchKernelGGL(gemm_lds, dim3(2, (N + 127) / 128), dim3(256), 0, stream,
                           Af, Wp, nf, N);
    } else {
        hipLaunchKernelGGL(gemm_fallback, dim3((N + 127) / 128, 2), dim3(256), 0,
                           stream, feat, W_fc, nf, N);
    }

    hipLaunchKernelGGL(edge_aggregate, dim3((N + 3) / 4), dim3(256), 0, stream,
                       rowptr, colind, pseudo, nf, mu, inv_sigma, bias, out, N);
}